// Round 2
// baseline (943.152 us; speedup 1.0000x reference)
//
#include <hip/hip_runtime.h>

#define S 2048
#define E 1024
#define H 16
#define D 64
#define KTOP 64
#define SCALE 0.125f

// ---------------------------------------------------------------------------
// GEMM: C = A @ W^T + bias.  A: MxK row-major (M=S, K=E), W: NxK row-major
// (N=E), C: MxN.  blockIdx.z selects among 3 (W,b,C) sets for fused QKV.
// Tile 64x64, BK=32, 256 threads, 4x4 per thread, register double-buffered
// staging (load tile k+1 -> regs while computing tile k).
// fp32 vector-ALU (no fp32-input MFMA on CDNA4).
// ---------------------------------------------------------------------------
__global__ __launch_bounds__(256) void gemm_nt_bias(
    const float* __restrict__ A,
    const float* __restrict__ W0, const float* __restrict__ W1, const float* __restrict__ W2,
    const float* __restrict__ b0, const float* __restrict__ b1, const float* __restrict__ b2,
    float* __restrict__ C0, float* __restrict__ C1, float* __restrict__ C2)
{
    constexpr int BM = 64, BN = 64, BK = 32;
    const int z = blockIdx.z;
    const float* W    = (z == 0) ? W0 : (z == 1) ? W1 : W2;
    const float* bias = (z == 0) ? b0 : (z == 1) ? b1 : b2;
    float*       C    = (z == 0) ? C0 : (z == 1) ? C1 : C2;

    // +4 pad keeps rows 16B-aligned for float4 reads and breaks store conflicts
    __shared__ float As[BK][BM + 4];
    __shared__ float Bs[BK][BN + 4];

    const int tid = threadIdx.x;
    const int tx = tid & 15;   // output col quad
    const int ty = tid >> 4;   // output row quad
    const int m0 = blockIdx.y * BM;
    const int n0 = blockIdx.x * BN;

    // staging address components (constant across K-steps)
    const int r0 = tid >> 3;           // tile row for qi=0  (0..31)
    const int r1 = (tid + 256) >> 3;   // tile row for qi=1  (32..63)
    const int cq = tid & 7;            // k-quad 0..7

    float acc[4][4] = {};
    float4 av0, av1, wv0, wv1;

    // prefetch tile 0 into registers
    {
        const int k0 = 0;
        av0 = *(const float4*)&A[(size_t)(m0 + r0) * E + k0 + cq * 4];
        av1 = *(const float4*)&A[(size_t)(m0 + r1) * E + k0 + cq * 4];
        wv0 = *(const float4*)&W[(size_t)(n0 + r0) * E + k0 + cq * 4];
        wv1 = *(const float4*)&W[(size_t)(n0 + r1) * E + k0 + cq * 4];
    }

    for (int k0 = 0; k0 < E; k0 += BK) {
        __syncthreads();
        // regs -> LDS (transposed to [k][m])
        As[cq * 4 + 0][r0] = av0.x; As[cq * 4 + 1][r0] = av0.y;
        As[cq * 4 + 2][r0] = av0.z; As[cq * 4 + 3][r0] = av0.w;
        As[cq * 4 + 0][r1] = av1.x; As[cq * 4 + 1][r1] = av1.y;
        As[cq * 4 + 2][r1] = av1.z; As[cq * 4 + 3][r1] = av1.w;
        Bs[cq * 4 + 0][r0] = wv0.x; Bs[cq * 4 + 1][r0] = wv0.y;
        Bs[cq * 4 + 2][r0] = wv0.z; Bs[cq * 4 + 3][r0] = wv0.w;
        Bs[cq * 4 + 0][r1] = wv1.x; Bs[cq * 4 + 1][r1] = wv1.y;
        Bs[cq * 4 + 2][r1] = wv1.z; Bs[cq * 4 + 3][r1] = wv1.w;
        __syncthreads();

        // prefetch next tile (global -> regs) while computing this one
        if (k0 + BK < E) {
            const int kn = k0 + BK;
            av0 = *(const float4*)&A[(size_t)(m0 + r0) * E + kn + cq * 4];
            av1 = *(const float4*)&A[(size_t)(m0 + r1) * E + kn + cq * 4];
            wv0 = *(const float4*)&W[(size_t)(n0 + r0) * E + kn + cq * 4];
            wv1 = *(const float4*)&W[(size_t)(n0 + r1) * E + kn + cq * 4];
        }

#pragma unroll
        for (int k = 0; k < BK; ++k) {
            const float4 a4 = *(const float4*)&As[k][ty * 4];
            const float4 b4 = *(const float4*)&Bs[k][tx * 4];
            const float aa[4] = {a4.x, a4.y, a4.z, a4.w};
            const float bb[4] = {b4.x, b4.y, b4.z, b4.w};
#pragma unroll
            for (int i = 0; i < 4; ++i)
#pragma unroll
                for (int j = 0; j < 4; ++j)
                    acc[i][j] = fmaf(aa[i], bb[j], acc[i][j]);
        }
    }

    const float4 bv = *(const float4*)&bias[n0 + tx * 4];
#pragma unroll
    for (int i = 0; i < 4; ++i) {
        float4 o;
        o.x = acc[i][0] + bv.x; o.y = acc[i][1] + bv.y;
        o.z = acc[i][2] + bv.z; o.w = acc[i][3] + bv.w;
        *(float4*)&C[(size_t)(m0 + ty * 4 + i) * E + n0 + tx * 4] = o;
    }
}

// ---------------------------------------------------------------------------
// Fused top-k attention.  One WG = 256 threads (4 waves) handles one head and
// 16 query rows (4 rows per wave).  Scores for all 2048 keys live in registers
// (32 per lane per row).  Top-64 via bitwise binary search on sortable uints.
// ---------------------------------------------------------------------------
__device__ __forceinline__ unsigned sortable_u(float f) {
    unsigned u = __float_as_uint(f);
    return (u & 0x80000000u) ? ~u : (u | 0x80000000u);
}
__device__ __forceinline__ float unsortable_f(unsigned su) {
    unsigned u = (su & 0x80000000u) ? (su & 0x7fffffffu) : ~su;
    return __uint_as_float(u);
}

__global__ __launch_bounds__(256, 2) void topk_attn(
    const float* __restrict__ Qp, const float* __restrict__ Kp,
    const float* __restrict__ Vp, float* __restrict__ AO)
{
    constexpr int CHUNK = 256;
    constexpr int NCH = S / CHUNK;   // 8

    __shared__ float Klds[D][CHUNK + 2];   // transposed [d][key], stride 258
    __shared__ float Qlds[16][D];
    __shared__ int   sIdx[16][KTOP];
    __shared__ float sW[16][KTOP];

    const int tid  = threadIdx.x;
    const int lane = tid & 63;
    const int wv   = tid >> 6;          // wave 0..3
    const int h    = blockIdx.y;
    const int q0   = blockIdx.x * 16;   // global query row base of WG
    const int row0 = wv * 4;            // local row base of this wave

    // ---- stage Q (pre-scaled) ----
    {
        const int r = tid >> 4, cq4 = tid & 15;
        float4 qv = *(const float4*)&Qp[(size_t)(q0 + r) * E + h * D + cq4 * 4];
        qv.x *= SCALE; qv.y *= SCALE; qv.z *= SCALE; qv.w *= SCALE;
        *(float4*)&Qlds[r][cq4 * 4] = qv;
    }

    float sc[4][32];
#pragma unroll
    for (int r = 0; r < 4; ++r)
#pragma unroll
        for (int j = 0; j < 32; ++j) sc[r][j] = 0.f;

    // ---- score phase: loop key chunks of 256 ----
#pragma unroll
    for (int c = 0; c < NCH; ++c) {
        const int base = c * CHUNK;
        __syncthreads();   // protect Klds (and, at c=0, publish Qlds)
#pragma unroll
        for (int p = 0; p < 16; ++p) {
            const int key = p * 16 + (tid >> 4);
            const int dq  = tid & 15;
            const float4 kv = *(const float4*)&Kp[(size_t)(base + key) * E + h * D + dq * 4];
            Klds[dq * 4 + 0][key] = kv.x;
            Klds[dq * 4 + 1][key] = kv.y;
            Klds[dq * 4 + 2][key] = kv.z;
            Klds[dq * 4 + 3][key] = kv.w;
        }
        __syncthreads();
#pragma unroll
        for (int dq = 0; dq < 16; ++dq) {
            const int d0 = dq * 4;
            float4 qr[4];
#pragma unroll
            for (int r = 0; r < 4; ++r) qr[r] = *(const float4*)&Qlds[row0 + r][d0];
#pragma unroll
            for (int dd = 0; dd < 4; ++dd) {
                const float2 ka = *(const float2*)&Klds[d0 + dd][2 * lane];
                const float2 kb = *(const float2*)&Klds[d0 + dd][CHUNK / 2 + 2 * lane];
#pragma unroll
                for (int r = 0; r < 4; ++r) {
                    const float q = ((const float*)&qr[r])[dd];
                    sc[r][c * 4 + 0] = fmaf(q, ka.x, sc[r][c * 4 + 0]);
                    sc[r][c * 4 + 1] = fmaf(q, ka.y, sc[r][c * 4 + 1]);
                    sc[r][c * 4 + 2] = fmaf(q, kb.x, sc[r][c * 4 + 2]);
                    sc[r][c * 4 + 3] = fmaf(q, kb.y, sc[r][c * 4 + 3]);
                }
            }
        }
    }

    // ---- convert scores to sortable uints in place; track per-row max ----
    unsigned msu[4] = {0u, 0u, 0u, 0u};
#pragma unroll
    for (int r = 0; r < 4; ++r)
#pragma unroll
        for (int j = 0; j < 32; ++j) {
            const unsigned suv = sortable_u(sc[r][j]);
            sc[r][j] = __uint_as_float(suv);
            if (suv > msu[r]) msu[r] = suv;
        }

    const unsigned long long below = (1ull << lane) - 1ull;
    float rz[4], rm[4];

#pragma unroll
    for (int r = 0; r < 4; ++r) {
        // wave max
        unsigned m = msu[r];
#pragma unroll
        for (int o = 32; o; o >>= 1) {
            const unsigned t = (unsigned)__shfl_xor((int)m, o, 64);
            if (t > m) m = t;
        }
        rm[r] = unsortable_f(m);

        // bitwise binary search for T = max t with count(su >= t) >= KTOP
        unsigned T = 0u;
        for (int b = 31; b >= 0; --b) {
            const unsigned cand = T | (1u << b);
            int cnt = 0;
#pragma unroll
            for (int j = 0; j < 32; ++j)
                cnt += (int)__popcll(__ballot(__float_as_uint(sc[r][j]) >= cand));
            if (cnt >= KTOP) {
                T = cand;
                if (cnt == KTOP) break;   // valid: count(>T)<=KTOP, ties fill rest
            }
        }

        // gather strictly-greater, then ties (==T) up to capacity
        int cprev = 0;
        float zs = 0.f;
#pragma unroll
        for (int j = 0; j < 32; ++j) {
            const unsigned suv = __float_as_uint(sc[r][j]);
            const bool sel = (suv > T);
            const unsigned long long mk = __ballot(sel);
            if (sel) {
                const int pos = cprev + (int)__popcll(mk & below);
                const float w = __expf(unsortable_f(suv) - rm[r]);
                const int key = (j >> 2) * CHUNK + ((j >> 1) & 1) * (CHUNK / 2) + 2 * lane + (j & 1);
                sIdx[row0 + r][pos] = key;
                sW[row0 + r][pos] = w;
                zs += w;
            }
            cprev += (int)__popcll(mk);
        }
#pragma unroll
        for (int j = 0; j < 32; ++j) {
            const unsigned suv = __float_as_uint(sc[r][j]);
            const bool sel = (suv == T);
            const unsigned long long mk = __ballot(sel);
            if (sel) {
                const int pos = cprev + (int)__popcll(mk & below);
                if (pos < KTOP) {
                    const float w = __expf(unsortable_f(suv) - rm[r]);
                    const int key = (j >> 2) * CHUNK + ((j >> 1) & 1) * (CHUNK / 2) + 2 * lane + (j & 1);
                    sIdx[row0 + r][pos] = key;
                    sW[row0 + r][pos] = w;
                    zs += w;
                }
            }
            cprev += (int)__popcll(mk);
        }
        // wave-sum of selected exp weights
#pragma unroll
        for (int o = 32; o; o >>= 1) zs += __shfl_xor(zs, o, 64);
        rz[r] = zs;
    }

    // ---- PV: out[d] = sum_j w_j * V[idx_j, d]; lane = d ----
    float pv[4] = {0.f, 0.f, 0.f, 0.f};
    const float* Vh = Vp + h * D + lane;
#pragma unroll 4
    for (int j = 0; j < KTOP; ++j) {
#pragma unroll
        for (int r = 0; r < 4; ++r) {
            const int ix = sIdx[row0 + r][j];
            const float w = sW[row0 + r][j];
            pv[r] = fmaf(w, Vh[(size_t)ix * E], pv[r]);
        }
    }
#pragma unroll
    for (int r = 0; r < 4; ++r)
        AO[(size_t)(q0 + row0 + r) * E + h * D + lane] = pv[r] * (1.f / rz[r]);
}

// ---------------------------------------------------------------------------
extern "C" void kernel_launch(void* const* d_in, const int* in_sizes, int n_in,
                              void* d_out, int out_size, void* d_ws, size_t ws_size,
                              hipStream_t stream) {
    const float* x  = (const float*)d_in[0];
    const float* Wq = (const float*)d_in[1];
    const float* bq = (const float*)d_in[2];
    const float* Wk = (const float*)d_in[3];
    const float* bk = (const float*)d_in[4];
    const float* Wv = (const float*)d_in[5];
    const float* bv = (const float*)d_in[6];
    const float* Wo = (const float*)d_in[7];
    const float* bo = (const float*)d_in[8];
    float* out = (float*)d_out;

    float* Qp = (float*)d_ws;          // S*E fp32 = 8 MB each
    float* Kp = Qp + (size_t)S * E;
    float* Vp = Kp + (size_t)S * E;
    float* AO = Vp + (size_t)S * E;    // total 32 MB of ws

    const dim3 blk(256);
    // fused Q,K,V projections (z = 0,1,2)
    gemm_nt_bias<<<dim3(E / 64, S / 64, 3), blk, 0, stream>>>(
        x, Wq, Wk, Wv, bq, bk, bv, Qp, Kp, Vp);
    // fused top-k attention
    topk_attn<<<dim3(S / 16, H), blk, 0, stream>>>(Qp, Kp, Vp, AO);
    // output projection
    gemm_nt_bias<<<dim3(E / 64, S / 64, 1), blk, 0, stream>>>(
        AO, Wo, Wo, Wo, bo, bo, bo, out, out, out);
}

// Round 3
// 927.610 us; speedup vs baseline: 1.0168x; 1.0168x over previous
//
#include <hip/hip_runtime.h>

#define S 2048
#define E 1024
#define H 16
#define D 64
#define KTOP 64
#define SCALE 0.125f

// ---------------------------------------------------------------------------
// GEMM: C = A @ W^T + bias.  A: MxK row-major (M=S, K=E), W: NxK row-major
// (N=E), C: MxN.  blockIdx.z selects among 3 (W,b,C) sets for fused QKV.
// Tile 64x64, BK=32, 256 threads, 4x4 per thread, register double-buffered
// staging.  fp32 vector-ALU (no fp32-input MFMA on CDNA4).
// UNCHANGED from round 2 (isolating the topk_attn spill fix).
// ---------------------------------------------------------------------------
__global__ __launch_bounds__(256) void gemm_nt_bias(
    const float* __restrict__ A,
    const float* __restrict__ W0, const float* __restrict__ W1, const float* __restrict__ W2,
    const float* __restrict__ b0, const float* __restrict__ b1, const float* __restrict__ b2,
    float* __restrict__ C0, float* __restrict__ C1, float* __restrict__ C2)
{
    constexpr int BM = 64, BN = 64, BK = 32;
    const int z = blockIdx.z;
    const float* W    = (z == 0) ? W0 : (z == 1) ? W1 : W2;
    const float* bias = (z == 0) ? b0 : (z == 1) ? b1 : b2;
    float*       C    = (z == 0) ? C0 : (z == 1) ? C1 : C2;

    __shared__ float As[BK][BM + 4];
    __shared__ float Bs[BK][BN + 4];

    const int tid = threadIdx.x;
    const int tx = tid & 15;
    const int ty = tid >> 4;
    const int m0 = blockIdx.y * BM;
    const int n0 = blockIdx.x * BN;

    const int r0 = tid >> 3;
    const int r1 = (tid + 256) >> 3;
    const int cq = tid & 7;

    float acc[4][4] = {};
    float4 av0, av1, wv0, wv1;

    {
        const int k0 = 0;
        av0 = *(const float4*)&A[(size_t)(m0 + r0) * E + k0 + cq * 4];
        av1 = *(const float4*)&A[(size_t)(m0 + r1) * E + k0 + cq * 4];
        wv0 = *(const float4*)&W[(size_t)(n0 + r0) * E + k0 + cq * 4];
        wv1 = *(const float4*)&W[(size_t)(n0 + r1) * E + k0 + cq * 4];
    }

    for (int k0 = 0; k0 < E; k0 += BK) {
        __syncthreads();
        As[cq * 4 + 0][r0] = av0.x; As[cq * 4 + 1][r0] = av0.y;
        As[cq * 4 + 2][r0] = av0.z; As[cq * 4 + 3][r0] = av0.w;
        As[cq * 4 + 0][r1] = av1.x; As[cq * 4 + 1][r1] = av1.y;
        As[cq * 4 + 2][r1] = av1.z; As[cq * 4 + 3][r1] = av1.w;
        Bs[cq * 4 + 0][r0] = wv0.x; Bs[cq * 4 + 1][r0] = wv0.y;
        Bs[cq * 4 + 2][r0] = wv0.z; Bs[cq * 4 + 3][r0] = wv0.w;
        Bs[cq * 4 + 0][r1] = wv1.x; Bs[cq * 4 + 1][r1] = wv1.y;
        Bs[cq * 4 + 2][r1] = wv1.z; Bs[cq * 4 + 3][r1] = wv1.w;
        __syncthreads();

        if (k0 + BK < E) {
            const int kn = k0 + BK;
            av0 = *(const float4*)&A[(size_t)(m0 + r0) * E + kn + cq * 4];
            av1 = *(const float4*)&A[(size_t)(m0 + r1) * E + kn + cq * 4];
            wv0 = *(const float4*)&W[(size_t)(n0 + r0) * E + kn + cq * 4];
            wv1 = *(const float4*)&W[(size_t)(n0 + r1) * E + kn + cq * 4];
        }

#pragma unroll
        for (int k = 0; k < BK; ++k) {
            const float4 a4 = *(const float4*)&As[k][ty * 4];
            const float4 b4 = *(const float4*)&Bs[k][tx * 4];
            const float aa[4] = {a4.x, a4.y, a4.z, a4.w};
            const float bb[4] = {b4.x, b4.y, b4.z, b4.w};
#pragma unroll
            for (int i = 0; i < 4; ++i)
#pragma unroll
                for (int j = 0; j < 4; ++j)
                    acc[i][j] = fmaf(aa[i], bb[j], acc[i][j]);
        }
    }

    const float4 bv = *(const float4*)&bias[n0 + tx * 4];
#pragma unroll
    for (int i = 0; i < 4; ++i) {
        float4 o;
        o.x = acc[i][0] + bv.x; o.y = acc[i][1] + bv.y;
        o.z = acc[i][2] + bv.z; o.w = acc[i][3] + bv.w;
        *(float4*)&C[(size_t)(m0 + ty * 4 + i) * E + n0 + tx * 4] = o;
    }
}

// ---------------------------------------------------------------------------
// Fused top-k attention.  One WG = 256 threads (4 waves), one head, 16 query
// rows (4 per wave).  Scores for all 2048 keys live in registers (128/lane).
//
// SPILL FIX (round 3): amdgpu_waves_per_eu(2,2) pins the occupancy target to
// 2 waves/EU -> hard 256-VGPR budget.  Round-2's __launch_bounds__(256,2)
// only set a MINIMUM of 2 waves/EU; the backend targeted 4 waves/EU, capped
// VGPRs at 128, and spilled sc[4][32] to scratch (FETCH 753 MB / WRITE
// 772 MB of pure spill traffic).  Staging also batched 4-wide to cut peak
// pressure (16 regs in flight, was 64).
// ---------------------------------------------------------------------------
__device__ __forceinline__ unsigned sortable_u(float f) {
    unsigned u = __float_as_uint(f);
    return (u & 0x80000000u) ? ~u : (u | 0x80000000u);
}
__device__ __forceinline__ float unsortable_f(unsigned su) {
    unsigned u = (su & 0x80000000u) ? (su & 0x7fffffffu) : ~su;
    return __uint_as_float(u);
}

__attribute__((amdgpu_waves_per_eu(2, 2)))
__global__ __launch_bounds__(256) void topk_attn(
    const float* __restrict__ Qp, const float* __restrict__ Kp,
    const float* __restrict__ Vp, float* __restrict__ AO)
{
    constexpr int CHUNK = 256;
    constexpr int NCH = S / CHUNK;   // 8

    __shared__ float Klds[D][CHUNK + 2];   // transposed [d][key], stride 258
    __shared__ float Qlds[16][D];
    __shared__ int   sIdx[16][KTOP];
    __shared__ float sW[16][KTOP];

    const int tid  = threadIdx.x;
    const int lane = tid & 63;
    const int wv   = tid >> 6;          // wave 0..3
    const int h    = blockIdx.y;
    const int q0   = blockIdx.x * 16;   // global query row base of WG
    const int row0 = wv * 4;            // local row base of this wave

    // ---- stage Q (pre-scaled) ----
    {
        const int r = tid >> 4, cq4 = tid & 15;
        float4 qv = *(const float4*)&Qp[(size_t)(q0 + r) * E + h * D + cq4 * 4];
        qv.x *= SCALE; qv.y *= SCALE; qv.z *= SCALE; qv.w *= SCALE;
        *(float4*)&Qlds[r][cq4 * 4] = qv;
    }

    float sc[4][32];
#pragma unroll
    for (int r = 0; r < 4; ++r)
#pragma unroll
        for (int j = 0; j < 32; ++j) sc[r][j] = 0.f;

    const int skey = tid >> 4;   // staging: key sub-index 0..15
    const int sdq  = tid & 15;   // staging: d-quad 0..15

    // ---- score phase: key chunks of 256 (unrolled: sc indices must stay
    //      compile-time constants or the array goes to scratch) ----
#pragma unroll
    for (int c = 0; c < NCH; ++c) {
        const int base = c * CHUNK;
        __syncthreads();   // protect Klds (and, at c=0, publish Qlds)
        // stage K transposed, 4 batches of 4 float4 loads (16 regs in flight)
#pragma unroll
        for (int pb = 0; pb < 4; ++pb) {
            float4 kv[4];
#pragma unroll
            for (int p = 0; p < 4; ++p) {
                const int key = (pb * 4 + p) * 16 + skey;
                kv[p] = *(const float4*)&Kp[(size_t)(base + key) * E + h * D + sdq * 4];
            }
#pragma unroll
            for (int p = 0; p < 4; ++p) {
                const int key = (pb * 4 + p) * 16 + skey;
                Klds[sdq * 4 + 0][key] = kv[p].x;
                Klds[sdq * 4 + 1][key] = kv[p].y;
                Klds[sdq * 4 + 2][key] = kv[p].z;
                Klds[sdq * 4 + 3][key] = kv[p].w;
            }
        }
        __syncthreads();
#pragma unroll
        for (int dq = 0; dq < 16; ++dq) {
            const int d0 = dq * 4;
            float4 qr[4];
#pragma unroll
            for (int r = 0; r < 4; ++r) qr[r] = *(const float4*)&Qlds[row0 + r][d0];
#pragma unroll
            for (int dd = 0; dd < 4; ++dd) {
                const float2 ka = *(const float2*)&Klds[d0 + dd][2 * lane];
                const float2 kb = *(const float2*)&Klds[d0 + dd][CHUNK / 2 + 2 * lane];
#pragma unroll
                for (int r = 0; r < 4; ++r) {
                    const float q = ((const float*)&qr[r])[dd];
                    sc[r][c * 4 + 0] = fmaf(q, ka.x, sc[r][c * 4 + 0]);
                    sc[r][c * 4 + 1] = fmaf(q, ka.y, sc[r][c * 4 + 1]);
                    sc[r][c * 4 + 2] = fmaf(q, kb.x, sc[r][c * 4 + 2]);
                    sc[r][c * 4 + 3] = fmaf(q, kb.y, sc[r][c * 4 + 3]);
                }
            }
        }
    }

    // ---- convert scores to sortable uints in place; track per-row max ----
    unsigned msu[4] = {0u, 0u, 0u, 0u};
#pragma unroll
    for (int r = 0; r < 4; ++r)
#pragma unroll
        for (int j = 0; j < 32; ++j) {
            const unsigned suv = sortable_u(sc[r][j]);
            sc[r][j] = __uint_as_float(suv);
            if (suv > msu[r]) msu[r] = suv;
        }

    const unsigned long long below = (1ull << lane) - 1ull;
    float rz[4], rm[4];

#pragma unroll
    for (int r = 0; r < 4; ++r) {
        // wave max
        unsigned m = msu[r];
#pragma unroll
        for (int o = 32; o; o >>= 1) {
            const unsigned t = (unsigned)__shfl_xor((int)m, o, 64);
            if (t > m) m = t;
        }
        rm[r] = unsortable_f(m);

        // bitwise binary search for T = max t with count(su >= t) >= KTOP
        unsigned T = 0u;
        for (int b = 31; b >= 0; --b) {
            const unsigned cand = T | (1u << b);
            int cnt = 0;
#pragma unroll
            for (int j = 0; j < 32; ++j)
                cnt += (int)__popcll(__ballot(__float_as_uint(sc[r][j]) >= cand));
            if (cnt >= KTOP) {
                T = cand;
                if (cnt == KTOP) break;   // valid: count(>T)<=KTOP, ties fill rest
            }
        }

        // gather strictly-greater, then ties (==T) up to capacity
        int cprev = 0;
        float zs = 0.f;
#pragma unroll
        for (int j = 0; j < 32; ++j) {
            const unsigned suv = __float_as_uint(sc[r][j]);
            const bool sel = (suv > T);
            const unsigned long long mk = __ballot(sel);
            if (sel) {
                const int pos = cprev + (int)__popcll(mk & below);
                const float w = __expf(unsortable_f(suv) - rm[r]);
                const int key = (j >> 2) * CHUNK + ((j >> 1) & 1) * (CHUNK / 2) + 2 * lane + (j & 1);
                sIdx[row0 + r][pos] = key;
                sW[row0 + r][pos] = w;
                zs += w;
            }
            cprev += (int)__popcll(mk);
        }
#pragma unroll
        for (int j = 0; j < 32; ++j) {
            const unsigned suv = __float_as_uint(sc[r][j]);
            const bool sel = (suv == T);
            const unsigned long long mk = __ballot(sel);
            if (sel) {
                const int pos = cprev + (int)__popcll(mk & below);
                if (pos < KTOP) {
                    const float w = __expf(unsortable_f(suv) - rm[r]);
                    const int key = (j >> 2) * CHUNK + ((j >> 1) & 1) * (CHUNK / 2) + 2 * lane + (j & 1);
                    sIdx[row0 + r][pos] = key;
                    sW[row0 + r][pos] = w;
                }
            }
            cprev += (int)__popcll(mk);
        }
        // recompute zs including capped ties is unnecessary: ties beyond
        // capacity are excluded from the reference softmax too (top_k keeps
        // exactly KTOP entries); sum selected weights across wave:
#pragma unroll
        for (int o = 32; o; o >>= 1) zs += __shfl_xor(zs, o, 64);
        rz[r] = zs;
    }

    __syncthreads();   // publish sIdx/sW (each wave wrote its own rows)

    // ---- PV: out[d] = sum_j w_j * V[idx_j, d]; lane = d ----
    float pv[4] = {0.f, 0.f, 0.f, 0.f};
    const float* Vh = Vp + h * D + lane;
#pragma unroll 4
    for (int j = 0; j < KTOP; ++j) {
#pragma unroll
        for (int r = 0; r < 4; ++r) {
            const int ix = sIdx[row0 + r][j];
            const float w = sW[row0 + r][j];
            pv[r] = fmaf(w, Vh[(size_t)ix * E], pv[r]);
        }
    }
#pragma unroll
    for (int r = 0; r < 4; ++r)
        AO[(size_t)(q0 + row0 + r) * E + h * D + lane] = pv[r] * (1.f / rz[r]);
}

// ---------------------------------------------------------------------------
extern "C" void kernel_launch(void* const* d_in, const int* in_sizes, int n_in,
                              void* d_out, int out_size, void* d_ws, size_t ws_size,
                              hipStream_t stream) {
    const float* x  = (const float*)d_in[0];
    const float* Wq = (const float*)d_in[1];
    const float* bq = (const float*)d_in[2];
    const float* Wk = (const float*)d_in[3];
    const float* bk = (const float*)d_in[4];
    const float* Wv = (const float*)d_in[5];
    const float* bv = (const float*)d_in[6];
    const float* Wo = (const float*)d_in[7];
    const float* bo = (const float*)d_in[8];
    float* out = (float*)d_out;

    float* Qp = (float*)d_ws;          // S*E fp32 = 8 MB each
    float* Kp = Qp + (size_t)S * E;
    float* Vp = Kp + (size_t)S * E;
    float* AO = Vp + (size_t)S * E;    // total 32 MB of ws

    const dim3 blk(256);
    gemm_nt_bias<<<dim3(E / 64, S / 64, 3), blk, 0, stream>>>(
        x, Wq, Wk, Wv, bq, bk, bv, Qp, Kp, Vp);
    topk_attn<<<dim3(S / 16, H), blk, 0, stream>>>(Qp, Kp, Vp, AO);
    gemm_nt_bias<<<dim3(E / 64, S / 64, 1), blk, 0, stream>>>(
        AO, Wo, Wo, Wo, bo, bo, bo, out, out, out);
}